// Round 8
// baseline (275.563 us; speedup 1.0000x reference)
//
#include <hip/hip_runtime.h>
#include <hip/hip_bf16.h>

typedef float f32x4 __attribute__((ext_vector_type(4)));
typedef short bf16x8 __attribute__((ext_vector_type(8)));

#define MFMA16(a, b, c) __builtin_amdgcn_mfma_f32_16x16x32_bf16(a, b, c, 0, 0, 0)

// Problem constants
constexpr int K1  = 940;    // IN_F
constexpr int KP2 = 1024;   // w2 K stride (zero-padded) = 4 quarters of 256
constexpr int NP  = 112;    // N=100 padded to 7 tiles of 16
constexpr int OSL = 136;    // out_s LDS row stride (bf16)

__device__ __forceinline__ float sigf(float x) { return 1.f / (1.f + __expf(-x)); }
__device__ __forceinline__ float tanhfast(float x) { return 2.f / (1.f + __expf(-2.f * x)) - 1.f; }

__device__ __forceinline__ short f2b(float x) {
  __hip_bfloat16 b = __float2bfloat16(x);
  return *reinterpret_cast<short*>(&b);
}

__device__ __forceinline__ bf16x8 mk8(float4 lo, float4 hi) {
  return bf16x8{f2b(lo.x), f2b(lo.y), f2b(lo.z), f2b(lo.w),
                f2b(hi.x), f2b(hi.y), f2b(hi.z), f2b(hi.w)};
}

// ---------------------------------------------------------------------------
// Prep: fold swapaxes(-1,-2) into the weights, convert fp32->bf16, zero-pad.
// ---------------------------------------------------------------------------
__global__ void prep_kernel(const float* __restrict__ lin_w,
                            const float* __restrict__ b_wih,
                            __hip_bfloat16* __restrict__ w2,
                            __hip_bfloat16* __restrict__ bw2) {
  int idx = blockIdx.x * 256 + threadIdx.x;
  if (idx < NP * KP2) {
    int n = idx >> 10, k = idx & 1023;
    float v = 0.f;
    if (n < 100 && k < K1) {
      int c10 = k / 94, rem = k - c10 * 94;
      int c2 = rem / 47, c47 = rem - c2 * 47;
      int f = c10 * 94 + c47 * 2 + c2;
      v = lin_w[n * K1 + f];
    }
    w2[idx] = __float2bfloat16(v);
  } else {
    int i2 = idx - NP * KP2;
    if (i2 < 64 * 128) {
      int g = i2 >> 7, k = i2 & 127;
      bw2[i2] = __float2bfloat16((k < 100) ? b_wih[g * 100 + k] : 0.f);
    }
  }
}

// ---------------------------------------------------------------------------
// R8: SPLIT kernels for 4x TLP on the GEMM + per-phase attribution.
// linear_gemm: block = 256 thr = 4 waves = 16 rows; wave w owns K-quarter
// [w*256,(w+1)*256) (w2 zero-padded past 940 -> quarters exact). 2048 blocks
// = 8192 waves = 32 waves/CU capacity (vs 8 in the fused design -- the one
// lever the compiler can't flatten). Partials reduced via LDS; bias+relu;
// out1 bf16 [32768][112] (cols 100..111 zeroed) to workspace.
// ---------------------------------------------------------------------------
__global__ __launch_bounds__(256)
void linear_gemm(const float* __restrict__ ch,
                 const __hip_bfloat16* __restrict__ w2,
                 const float* __restrict__ lin_b,
                 __hip_bfloat16* __restrict__ out1) {
  __shared__ float red[4][16][116];   // 29696 B; stride 116 -> 2-way banks
  const int tid = threadIdx.x;
  const int w = tid >> 6, lane = tid & 63;
  const int l16 = lane & 15, bq = lane >> 4;
  const int mbase = blockIdx.x * 16;
  const int wkb = w * 256;
  const float* ar = ch + (long)(mbase + l16) * K1 + wkb + bq * 8;

  f32x4 acc[7] = {};
  float4 Aa[2][2];     // A ping-pong: 8 f32/lane per k-step
  bf16x8 Bb[2][7];     // B ping-pong: 7 n-tiles per k-step

  auto ldA = [&](int ks, float4* d) {
    const float* p = ar + ks * 32;
    const int k0 = wkb + ks * 32 + bq * 8;
    if (k0 + 8 <= K1) {
      d[0] = *reinterpret_cast<const float4*>(p);
      d[1] = *reinterpret_cast<const float4*>(p + 4);
    } else {            // boundary (wave 3 only): per-element mask, no OOB
      float t[8];
#pragma unroll
      for (int j = 0; j < 8; ++j) t[j] = (k0 + j < K1) ? p[j] : 0.f;
      d[0] = float4{t[0], t[1], t[2], t[3]};
      d[1] = float4{t[4], t[5], t[6], t[7]};
    }
  };
  auto ldB = [&](int ks, bf16x8* d) {
#pragma unroll
    for (int nt = 0; nt < 7; ++nt)
      d[nt] = *reinterpret_cast<const bf16x8*>(
          &w2[(nt * 16 + l16) * KP2 + wkb + ks * 32 + bq * 8]);
  };

  ldA(0, Aa[0]);
  ldB(0, Bb[0]);
#pragma unroll
  for (int ks = 0; ks < 8; ++ks) {
    if (ks < 7) { ldA(ks + 1, Aa[(ks + 1) & 1]); ldB(ks + 1, Bb[(ks + 1) & 1]); }
    bf16x8 a = mk8(Aa[ks & 1][0], Aa[ks & 1][1]);
#pragma unroll
    for (int nt = 0; nt < 7; ++nt) acc[nt] = MFMA16(a, Bb[ks & 1][nt], acc[nt]);
  }

  // scatter partials, reduce 4-way, bias+relu, store bf16
#pragma unroll
  for (int nt = 0; nt < 7; ++nt)
#pragma unroll
    for (int r = 0; r < 4; ++r)
      red[w][bq * 4 + r][nt * 16 + l16] = acc[nt][r];
  __syncthreads();

#pragma unroll
  for (int i = 0; i < 7; ++i) {
    const int e = i * 256 + tid;          // 1792 = 16 rows x 112 cols
    const int row = e / 112, col = e - row * 112;
    float s = red[0][row][col] + red[1][row][col] +
              red[2][row][col] + red[3][row][col];
    float v = (col < 100) ? fmaxf(s + lin_b[col], 0.f) : 0.f;
    out1[(long)(mbase + row) * 112 + col] = __float2bfloat16(v);
  }
}

// ---------------------------------------------------------------------------
// lstm_kernel: stage out1 rows -> LDS (zero-pad cols to 128), then R7's
// Phases B (xg GEMM), C (beats LSTM), D (bars biLSTM) verbatim.
// Block = 256 thr = 4 waves = 64 rows = 8 frac-seqs = 2 bar-seqs.
// ---------------------------------------------------------------------------
__global__ __launch_bounds__(256)
void lstm_kernel(const __hip_bfloat16* __restrict__ out1,
                 const __hip_bfloat16* __restrict__ bw2,
                 const float* __restrict__ bih,
                 const float* __restrict__ bhh,
                 const float* __restrict__ whh,
                 const float* __restrict__ fwih, const float* __restrict__ fwhh,
                 const float* __restrict__ fbih, const float* __restrict__ fbhh,
                 const float* __restrict__ rwih, const float* __restrict__ rwhh,
                 const float* __restrict__ rbih, const float* __restrict__ rbhh,
                 float* __restrict__ beats,
                 float* __restrict__ bars) {
  __shared__ __align__(16) __hip_bfloat16 out_s[64 * OSL];   // 17408 B
  __shared__ float xg_s[64 * 65];                            // 16640 B
  __shared__ float hlast[8][16];
  __shared__ float hb[2][32];
  __shared__ float gact[2][128];

  const int tid = threadIdx.x;
  const int w = tid >> 6, lane = tid & 63;
  const int l16 = lane & 15, bq = lane >> 4;
  const long rbase = (long)blockIdx.x * 64;

  // stage out1 [64][112] -> out_s [64][OSL], zero cols 112..127
#pragma unroll
  for (int it = 0; it < 4; ++it) {
    const int e = it * 256 + tid;        // 896 = 64 rows x 14 groups
    if (e < 896) {
      const int row = e / 14, g = e - row * 14;
      *reinterpret_cast<bf16x8*>(&out_s[row * OSL + g * 8]) =
          *reinterpret_cast<const bf16x8*>(&out1[(rbase + row) * 112 + g * 8]);
    }
  }
  if (tid < 128) {
    const int row = tid >> 1, c0 = 112 + (tid & 1) * 8;
    bf16x8 z = {0, 0, 0, 0, 0, 0, 0, 0};
    *reinterpret_cast<bf16x8*>(&out_s[row * OSL + c0]) = z;
  }
  __syncthreads();

  // ---- Phase B: xg[16 rows][64 gates], wave-private rows ----
  {
    bf16x8 av[4];
#pragma unroll
    for (int s = 0; s < 4; ++s)
      av[s] = *reinterpret_cast<const bf16x8*>(&out_s[(w * 16 + l16) * OSL + s * 32 + bq * 8]);
    f32x4 xacc[4] = {};
#pragma unroll
    for (int gt = 0; gt < 4; ++gt) {
#pragma unroll
      for (int s = 0; s < 4; ++s) {
        bf16x8 b = *reinterpret_cast<const bf16x8*>(&bw2[(gt * 16 + l16) * 128 + s * 32 + bq * 8]);
        xacc[gt] = MFMA16(av[s], b, xacc[gt]);
      }
    }
#pragma unroll
    for (int gt = 0; gt < 4; ++gt) {
      const int gate = gt * 16 + l16;
      const float bias = bih[gate] + bhh[gate];
#pragma unroll
      for (int r = 0; r < 4; ++r)
        xg_s[(w * 16 + bq * 4 + r) * 65 + gate] = xacc[gt][r] + bias;
    }
  }

  // ---- Phase C: beats LSTM, 2 sequences per wave, interleaved ----
  {
    const int cell = lane & 15;
    float wr[16];
#pragma unroll
    for (int u = 0; u < 16; ++u) wr[u] = whh[lane * 16 + u];
    float xv0[8], xv1[8];
#pragma unroll
    for (int t = 0; t < 8; ++t) {
      xv0[t] = xg_s[(w * 16 + t) * 65 + lane];
      xv1[t] = xg_s[(w * 16 + 8 + t) * 65 + lane];
    }
    float h0[16], h1[16];
#pragma unroll
    for (int u = 0; u < 16; ++u) { h0[u] = 0.f; h1[u] = 0.f; }
    float c0 = 0.f, c1 = 0.f;
    const long sg0 = (long)blockIdx.x * 8 + 2 * w;
    const long sg1 = sg0 + 1;
#pragma unroll
    for (int t = 0; t < 8; ++t) {
      float p0 = xv0[t], p1 = xv1[t];
#pragma unroll
      for (int u = 0; u < 16; ++u) { p0 += wr[u] * h0[u]; p1 += wr[u] * h1[u]; }
      const bool istanh = (lane >= 32 && lane < 48);
      float a0 = istanh ? tanhfast(p0) : sigf(p0);
      float a1 = istanh ? tanhfast(p1) : sigf(p1);
      float gi0 = __shfl(a0, cell),      gi1 = __shfl(a1, cell);
      float gf0 = __shfl(a0, cell + 16), gf1 = __shfl(a1, cell + 16);
      float gg0 = __shfl(a0, cell + 32), gg1 = __shfl(a1, cell + 32);
      float go0 = __shfl(a0, cell + 48), go1 = __shfl(a1, cell + 48);
      c0 = gf0 * c0 + gi0 * gg0;
      c1 = gf1 * c1 + gi1 * gg1;
      float hn0 = go0 * tanhfast(c0);
      float hn1 = go1 * tanhfast(c1);
#pragma unroll
      for (int u = 0; u < 16; ++u) { h0[u] = __shfl(hn0, u); h1[u] = __shfl(hn1, u); }
      if (lane < 16) {
        beats[sg0 * 128 + t * 16 + lane] = hn0;
        beats[sg1 * 128 + t * 16 + lane] = hn1;
        if (t == 7) {
          hlast[2 * w][lane]     = hn0;
          hlast[2 * w + 1][lane] = hn1;
        }
      }
    }
  }
  __syncthreads();  // publish hlast

  // ---- Phase D: bars biLSTM for this block's 2 bar-sequences ----
  {
    const int dir = tid >> 7, g = tid & 127;
    const float* wihp = dir ? rwih : fwih;
    const float* whhp = dir ? rwhh : fwhh;
    const float bias = dir ? (rbih[g] + rbhh[g]) : (fbih[g] + fbhh[g]);
    float wi[16], wh[32];
#pragma unroll
    for (int u = 0; u < 16; ++u) wi[u] = wihp[g * 16 + u];
#pragma unroll
    for (int u = 0; u < 32; ++u) wh[u] = whhp[g * 32 + u];
    for (int b2 = 0; b2 < 2; ++b2) {
      const int n = blockIdx.x * 2 + b2;
      float c = 0.f;
      if (g < 32) hb[dir][g] = 0.f;
      __syncthreads();
      for (int t = 0; t < 4; ++t) {
        const int tt = dir ? (3 - t) : t;
        float pre = bias;
#pragma unroll
        for (int u = 0; u < 16; ++u) pre += wi[u] * hlast[b2 * 4 + tt][u];
#pragma unroll
        for (int u = 0; u < 32; ++u) pre += wh[u] * hb[dir][u];
        gact[dir][g] = (g >= 64 && g < 96) ? tanhfast(pre) : sigf(pre);
        __syncthreads();
        if (g < 32) {
          c = gact[dir][32 + g] * c + gact[dir][g] * gact[dir][64 + g];
          float hn = gact[dir][96 + g] * tanhfast(c);
          hb[dir][g] = hn;
          bars[(n * 4 + tt) * 64 + dir * 32 + g] = hn;
        }
        __syncthreads();
      }
    }
  }
}

extern "C" void kernel_launch(void* const* d_in, const int* in_sizes, int n_in,
                              void* d_out, int out_size, void* d_ws, size_t ws_size,
                              hipStream_t stream) {
  const float* ch    = (const float*)d_in[0];
  const float* lin_w = (const float*)d_in[1];
  const float* lin_b = (const float*)d_in[2];
  const float* b_wih = (const float*)d_in[3];
  const float* b_whh = (const float*)d_in[4];
  const float* b_bih = (const float*)d_in[5];
  const float* b_bhh = (const float*)d_in[6];
  const float* f_wih = (const float*)d_in[7];
  const float* f_whh = (const float*)d_in[8];
  const float* f_bih = (const float*)d_in[9];
  const float* f_bhh = (const float*)d_in[10];
  const float* r_wih = (const float*)d_in[11];
  const float* r_whh = (const float*)d_in[12];
  const float* r_bih = (const float*)d_in[13];
  const float* r_bhh = (const float*)d_in[14];

  char* ws = (char*)d_ws;
  __hip_bfloat16* w2   = (__hip_bfloat16*)ws;             // 229376 B
  __hip_bfloat16* bw2  = (__hip_bfloat16*)(ws + 229376);  // 16384 B
  __hip_bfloat16* out1 = (__hip_bfloat16*)(ws + 245760);  // 32768*112*2 = 7340032 B
  float*          out  = (float*)d_out;

  prep_kernel<<<480, 256, 0, stream>>>(lin_w, b_wih, w2, bw2);
  linear_gemm<<<2048, 256, 0, stream>>>(ch, w2, lin_b, out1);
  lstm_kernel<<<512, 256, 0, stream>>>(out1, bw2, b_bih, b_bhh, b_whh,
                                       f_wih, f_whh, f_bih, f_bhh,
                                       r_wih, r_whh, r_bih, r_bhh,
                                       out, out + 524288);
}

// Round 9
// 234.109 us; speedup vs baseline: 1.1771x; 1.1771x over previous
//
#include <hip/hip_runtime.h>
#include <hip/hip_bf16.h>

typedef float f32x4 __attribute__((ext_vector_type(4)));
typedef short bf16x8 __attribute__((ext_vector_type(8)));
typedef short bf16x4 __attribute__((ext_vector_type(4)));

#define MFMA16(a, b, c) __builtin_amdgcn_mfma_f32_16x16x32_bf16(a, b, c, 0, 0, 0)

// Problem constants
constexpr int K1  = 940;     // IN_F
constexpr int NP  = 112;     // N=100 padded to 7 tiles of 16
constexpr int OSL = 136;     // out_s LDS row stride (bf16), lstm kernel
constexpr int CHE = 14336;   // w2c elements per chunk (112 rows x 128)
constexpr int CHB = 28672;   // w2c bytes per chunk

__device__ __forceinline__ float sigf(float x) { return 1.f / (1.f + __expf(-x)); }
__device__ __forceinline__ float tanhfast(float x) { return 2.f / (1.f + __expf(-2.f * x)) - 1.f; }

__device__ __forceinline__ short f2b(float x) {
  __hip_bfloat16 b = __float2bfloat16(x);
  return *reinterpret_cast<short*>(&b);
}

// global -> LDS direct DMA, 16B per lane. LDS dest is wave-uniform base
// (HW adds lane*16); global src is per-lane. Compiler cannot sink this.
__device__ __forceinline__ void gl_lds16(const void* g, void* l) {
  __builtin_amdgcn_global_load_lds(
      (const __attribute__((address_space(1))) unsigned int*)g,
      (__attribute__((address_space(3))) unsigned int*)l, 16, 0, 0);
}

// ---------------------------------------------------------------------------
// Prep: fold swapaxes(-1,-2) into weights; emit w2c CHUNK-MAJOR [8][112][128]
// bf16, PRE-SWIZZLED within each row (element kk ^= (n&7)<<3, i.e. byte
// ^= (n&7)<<4) so a linear global_load_lds copy lands bank-conflict-free for
// the GEMM's swizzled ds_read_b128 frag reads (rule: linear dest +
// inverse-swizzled source + swizzle on read). bw2 unchanged.
// ---------------------------------------------------------------------------
__global__ void prep_kernel(const float* __restrict__ lin_w,
                            const float* __restrict__ b_wih,
                            __hip_bfloat16* __restrict__ w2c,
                            __hip_bfloat16* __restrict__ bw2) {
  int idx = blockIdx.x * 256 + threadIdx.x;
  if (idx < NP * 1024) {
    int n = idx >> 10, k = idx & 1023;
    float v = 0.f;
    if (n < 100 && k < K1) {
      int c10 = k / 94, rem = k - c10 * 94;
      int c2 = rem / 47, c47 = rem - c2 * 47;
      int f = c10 * 94 + c47 * 2 + c2;
      v = lin_w[n * K1 + f];
    }
    int c = k >> 7, kk = k & 127;
    w2c[c * CHE + n * 128 + (kk ^ ((n & 7) << 3))] = __float2bfloat16(v);
  } else {
    int i2 = idx - NP * 1024;
    if (i2 < 64 * 128) {
      int g = i2 >> 7, k = i2 & 127;
      bw2[i2] = __float2bfloat16((k < 100) ? b_wih[g * 100 + k] : 0.f);
    }
  }
}

// ---------------------------------------------------------------------------
// R9 GEMM: B via global_load_lds DMA (double-buffered LDS), A via coalesced
// reg-stage -> swizzled wave-private LDS tile (R7 scheme). Wave owns 16 rows
// x 112 cols x full K; no split-K, no reduce. One vmcnt(0)+barrier per
// 128-k chunk; DMA+A loads for c+1 issued before compute of c.
// LDS: As 16384 + Bs 2*28672 = 73728 B -> 2 blocks/CU.
// ---------------------------------------------------------------------------
__global__ __launch_bounds__(256, 2)
void linear_gemm(const float* __restrict__ ch,
                 const __hip_bfloat16* __restrict__ w2c,
                 const float* __restrict__ lin_b,
                 __hip_bfloat16* __restrict__ out1) {
  __shared__ __align__(16) char smem[73728];
  char* As = smem;            // 64 rows x 256 B, swizzled, wave-private rows
  char* Bs = smem + 16384;    // 2 x 28672 B, swizzled (via pre-swz source)

  const int tid = threadIdx.x;
  const int w = tid >> 6, lane = tid & 63;
  const int l16 = lane & 15, bq = lane >> 4;
  const int row0 = blockIdx.x * 64 + w * 16;

  // ---- A: coalesced loads (1 KB/instr = rows {2j,2j+1} full 512B) ----
  float4 rA[8];
  const float4 f40{0.f, 0.f, 0.f, 0.f};
  const int acolf = (lane & 31) * 4;
  const float* asrc = ch + (long)(row0 + (lane >> 5)) * K1 + acolf;
  auto ldA = [&](int c) {
    const float* p = asrc + c * 128;
    if (c < 7) {
#pragma unroll
      for (int j = 0; j < 8; ++j)
        rA[j] = *reinterpret_cast<const float4*>(p + (long)j * 2 * K1);
    } else {  // chunk 7: cols 896+acolf..+3 valid iff acolf < 44
      const bool ok = acolf < 44;
#pragma unroll
      for (int j = 0; j < 8; ++j)
        rA[j] = ok ? *reinterpret_cast<const float4*>(p + (long)j * 2 * K1) : f40;
    }
  };
  auto stA = [&]() {
#pragma unroll
    for (int j = 0; j < 8; ++j) {
      const int row = w * 16 + (lane >> 5) + 2 * j;
      const int byte = row * 256 + (((lane & 31) * 8) ^ ((row & 7) << 4));
      bf16x4 v = {f2b(rA[j].x), f2b(rA[j].y), f2b(rA[j].z), f2b(rA[j].w)};
      *reinterpret_cast<bf16x4*>(As + byte) = v;
    }
  };

  // ---- B: 7 DMA instrs per wave per chunk (wave w copies bytes
  // [w*7168,(w+1)*7168) of the 28672 B chunk; linear, pre-swizzled src) ----
  auto dmaB = [&](int c, int buf) {
    const __hip_bfloat16* src = w2c + c * CHE + w * 3584 + lane * 8;
    char* dst = Bs + buf * CHB + w * 7168;
#pragma unroll
    for (int j = 0; j < 7; ++j)
      gl_lds16(src + j * 512, dst + j * 1024);
  };

  // ---- prologue: chunk 0 ----
  ldA(0);
  dmaB(0, 0);
  stA();  // compiler auto-waits rA's vmcnt (A loads are oldest? no: issued
          // first, so its wait leaves DMA outstanding only if counted; safe
          // either way -- correctness from the full drain below)
  asm volatile("s_waitcnt vmcnt(0) lgkmcnt(0)" ::: "memory");
  __builtin_amdgcn_s_barrier();
  __builtin_amdgcn_sched_barrier(0);

  f32x4 acc[7] = {};
  const int fsw = (l16 & 7) << 4;
  const int abase = (w * 16 + l16) * 256;

#pragma unroll
  for (int c = 0; c < 8; ++c) {
    if (c < 7) {
      ldA(c + 1);              // 8 vmem -> rA (regs)
      dmaB(c + 1, (c + 1) & 1);  // 7 vmem -> LDS DMA, can't be sunk
    }
    const char* Bp = Bs + (c & 1) * CHB;
#pragma unroll
    for (int ks = 0; ks < 4; ++ks) {
      const int ko = (ks * 64 + bq * 16) ^ fsw;
      bf16x8 a = *reinterpret_cast<const bf16x8*>(As + abase + ko);
#pragma unroll
      for (int nt = 0; nt < 7; ++nt) {
        bf16x8 b = *reinterpret_cast<const bf16x8*>(Bp + (nt * 16 + l16) * 256 + ko);
        acc[nt] = MFMA16(a, b, acc[nt]);
      }
    }
    asm volatile("s_waitcnt lgkmcnt(0)" ::: "memory");  // frag reads drained
    if (c < 7) stA();  // overwrite own A tile (wave-private, reads done)
    asm volatile("s_waitcnt vmcnt(0) lgkmcnt(0)" ::: "memory");
    __builtin_amdgcn_s_barrier();   // publish Bs[(c+1)&1] to all waves
    __builtin_amdgcn_sched_barrier(0);
  }

  // ---- epilogue: bias + relu -> out1 bf16 [32768][112] ----
#pragma unroll
  for (int nt = 0; nt < 7; ++nt) {
    const int col = nt * 16 + l16;
    const float bias = (col < 100) ? lin_b[col] : 0.f;
#pragma unroll
    for (int r = 0; r < 4; ++r) {
      float v = (col < 100) ? fmaxf(acc[nt][r] + bias, 0.f) : 0.f;
      out1[(long)(row0 + bq * 4 + r) * 112 + col] = __float2bfloat16(v);
    }
  }
}

// ---------------------------------------------------------------------------
// lstm_kernel (unchanged from R8): stage out1 -> LDS, xg GEMM, beats LSTM,
// bars biLSTM. Block = 256 thr = 4 waves = 64 rows = 8 frac-seqs = 2 bars.
// ---------------------------------------------------------------------------
__global__ __launch_bounds__(256)
void lstm_kernel(const __hip_bfloat16* __restrict__ out1,
                 const __hip_bfloat16* __restrict__ bw2,
                 const float* __restrict__ bih,
                 const float* __restrict__ bhh,
                 const float* __restrict__ whh,
                 const float* __restrict__ fwih, const float* __restrict__ fwhh,
                 const float* __restrict__ fbih, const float* __restrict__ fbhh,
                 const float* __restrict__ rwih, const float* __restrict__ rwhh,
                 const float* __restrict__ rbih, const float* __restrict__ rbhh,
                 float* __restrict__ beats,
                 float* __restrict__ bars) {
  __shared__ __align__(16) __hip_bfloat16 out_s[64 * OSL];   // 17408 B
  __shared__ float xg_s[64 * 65];                            // 16640 B
  __shared__ float hlast[8][16];
  __shared__ float hb[2][32];
  __shared__ float gact[2][128];

  const int tid = threadIdx.x;
  const int w = tid >> 6, lane = tid & 63;
  const int l16 = lane & 15, bq = lane >> 4;
  const long rbase = (long)blockIdx.x * 64;

  // stage out1 [64][112] -> out_s [64][OSL], zero cols 112..127
#pragma unroll
  for (int it = 0; it < 4; ++it) {
    const int e = it * 256 + tid;        // 896 = 64 rows x 14 groups
    if (e < 896) {
      const int row = e / 14, g = e - row * 14;
      *reinterpret_cast<bf16x8*>(&out_s[row * OSL + g * 8]) =
          *reinterpret_cast<const bf16x8*>(&out1[(rbase + row) * 112 + g * 8]);
    }
  }
  if (tid < 128) {
    const int row = tid >> 1, c0 = 112 + (tid & 1) * 8;
    bf16x8 z = {0, 0, 0, 0, 0, 0, 0, 0};
    *reinterpret_cast<bf16x8*>(&out_s[row * OSL + c0]) = z;
  }
  __syncthreads();

  // ---- Phase B: xg[16 rows][64 gates], wave-private rows ----
  {
    bf16x8 av[4];
#pragma unroll
    for (int s = 0; s < 4; ++s)
      av[s] = *reinterpret_cast<const bf16x8*>(&out_s[(w * 16 + l16) * OSL + s * 32 + bq * 8]);
    f32x4 xacc[4] = {};
#pragma unroll
    for (int gt = 0; gt < 4; ++gt) {
#pragma unroll
      for (int s = 0; s < 4; ++s) {
        bf16x8 b = *reinterpret_cast<const bf16x8*>(&bw2[(gt * 16 + l16) * 128 + s * 32 + bq * 8]);
        xacc[gt] = MFMA16(av[s], b, xacc[gt]);
      }
    }
#pragma unroll
    for (int gt = 0; gt < 4; ++gt) {
      const int gate = gt * 16 + l16;
      const float bias = bih[gate] + bhh[gate];
#pragma unroll
      for (int r = 0; r < 4; ++r)
        xg_s[(w * 16 + bq * 4 + r) * 65 + gate] = xacc[gt][r] + bias;
    }
  }

  // ---- Phase C: beats LSTM, 2 sequences per wave, interleaved ----
  {
    const int cell = lane & 15;
    float wr[16];
#pragma unroll
    for (int u = 0; u < 16; ++u) wr[u] = whh[lane * 16 + u];
    float xv0[8], xv1[8];
#pragma unroll
    for (int t = 0; t < 8; ++t) {
      xv0[t] = xg_s[(w * 16 + t) * 65 + lane];
      xv1[t] = xg_s[(w * 16 + 8 + t) * 65 + lane];
    }
    float h0[16], h1[16];
#pragma unroll
    for (int u = 0; u < 16; ++u) { h0[u] = 0.f; h1[u] = 0.f; }
    float c0 = 0.f, c1 = 0.f;
    const long sg0 = (long)blockIdx.x * 8 + 2 * w;
    const long sg1 = sg0 + 1;
#pragma unroll
    for (int t = 0; t < 8; ++t) {
      float p0 = xv0[t], p1 = xv1[t];
#pragma unroll
      for (int u = 0; u < 16; ++u) { p0 += wr[u] * h0[u]; p1 += wr[u] * h1[u]; }
      const bool istanh = (lane >= 32 && lane < 48);
      float a0 = istanh ? tanhfast(p0) : sigf(p0);
      float a1 = istanh ? tanhfast(p1) : sigf(p1);
      float gi0 = __shfl(a0, cell),      gi1 = __shfl(a1, cell);
      float gf0 = __shfl(a0, cell + 16), gf1 = __shfl(a1, cell + 16);
      float gg0 = __shfl(a0, cell + 32), gg1 = __shfl(a1, cell + 32);
      float go0 = __shfl(a0, cell + 48), go1 = __shfl(a1, cell + 48);
      c0 = gf0 * c0 + gi0 * gg0;
      c1 = gf1 * c1 + gi1 * gg1;
      float hn0 = go0 * tanhfast(c0);
      float hn1 = go1 * tanhfast(c1);
#pragma unroll
      for (int u = 0; u < 16; ++u) { h0[u] = __shfl(hn0, u); h1[u] = __shfl(hn1, u); }
      if (lane < 16) {
        beats[sg0 * 128 + t * 16 + lane] = hn0;
        beats[sg1 * 128 + t * 16 + lane] = hn1;
        if (t == 7) {
          hlast[2 * w][lane]     = hn0;
          hlast[2 * w + 1][lane] = hn1;
        }
      }
    }
  }
  __syncthreads();  // publish hlast

  // ---- Phase D: bars biLSTM for this block's 2 bar-sequences ----
  {
    const int dir = tid >> 7, g = tid & 127;
    const float* wihp = dir ? rwih : fwih;
    const float* whhp = dir ? rwhh : fwhh;
    const float bias = dir ? (rbih[g] + rbhh[g]) : (fbih[g] + fbhh[g]);
    float wi[16], wh[32];
#pragma unroll
    for (int u = 0; u < 16; ++u) wi[u] = wihp[g * 16 + u];
#pragma unroll
    for (int u = 0; u < 32; ++u) wh[u] = whhp[g * 32 + u];
    for (int b2 = 0; b2 < 2; ++b2) {
      const int n = blockIdx.x * 2 + b2;
      float c = 0.f;
      if (g < 32) hb[dir][g] = 0.f;
      __syncthreads();
      for (int t = 0; t < 4; ++t) {
        const int tt = dir ? (3 - t) : t;
        float pre = bias;
#pragma unroll
        for (int u = 0; u < 16; ++u) pre += wi[u] * hlast[b2 * 4 + tt][u];
#pragma unroll
        for (int u = 0; u < 32; ++u) pre += wh[u] * hb[dir][u];
        gact[dir][g] = (g >= 64 && g < 96) ? tanhfast(pre) : sigf(pre);
        __syncthreads();
        if (g < 32) {
          c = gact[dir][32 + g] * c + gact[dir][g] * gact[dir][64 + g];
          float hn = gact[dir][96 + g] * tanhfast(c);
          hb[dir][g] = hn;
          bars[(n * 4 + tt) * 64 + dir * 32 + g] = hn;
        }
        __syncthreads();
      }
    }
  }
}

extern "C" void kernel_launch(void* const* d_in, const int* in_sizes, int n_in,
                              void* d_out, int out_size, void* d_ws, size_t ws_size,
                              hipStream_t stream) {
  const float* ch    = (const float*)d_in[0];
  const float* lin_w = (const float*)d_in[1];
  const float* lin_b = (const float*)d_in[2];
  const float* b_wih = (const float*)d_in[3];
  const float* b_whh = (const float*)d_in[4];
  const float* b_bih = (const float*)d_in[5];
  const float* b_bhh = (const float*)d_in[6];
  const float* f_wih = (const float*)d_in[7];
  const float* f_whh = (const float*)d_in[8];
  const float* f_bih = (const float*)d_in[9];
  const float* f_bhh = (const float*)d_in[10];
  const float* r_wih = (const float*)d_in[11];
  const float* r_whh = (const float*)d_in[12];
  const float* r_bih = (const float*)d_in[13];
  const float* r_bhh = (const float*)d_in[14];

  char* ws = (char*)d_ws;
  __hip_bfloat16* w2c  = (__hip_bfloat16*)ws;             // 8*112*128*2 = 229376 B
  __hip_bfloat16* bw2  = (__hip_bfloat16*)(ws + 229376);  // 16384 B
  __hip_bfloat16* out1 = (__hip_bfloat16*)(ws + 245760);  // 32768*112*2 = 7340032 B
  float*          out  = (float*)d_out;

  prep_kernel<<<480, 256, 0, stream>>>(lin_w, b_wih, w2c, bw2);
  linear_gemm<<<512, 256, 0, stream>>>(ch, w2c, lin_b, out1);
  lstm_kernel<<<512, 256, 0, stream>>>(out1, bw2, b_bih, b_bhh, b_whh,
                                       f_wih, f_whh, f_bih, f_bhh,
                                       r_wih, r_whh, r_bih, r_bhh,
                                       out, out + 524288);
}

// Round 10
// 226.727 us; speedup vs baseline: 1.2154x; 1.0326x over previous
//
#include <hip/hip_runtime.h>
#include <hip/hip_bf16.h>

typedef float f32x4 __attribute__((ext_vector_type(4)));
typedef short bf16x8 __attribute__((ext_vector_type(8)));

#define MFMA16(a, b, c) __builtin_amdgcn_mfma_f32_16x16x32_bf16(a, b, c, 0, 0, 0)

// Problem constants
constexpr int K1  = 940;     // IN_F
constexpr int NP  = 112;     // N=100 padded to 7 tiles of 16
constexpr int OSL = 136;     // out_s LDS row stride (bf16), lstm kernel
constexpr int BCH = 14336;   // B chunk bytes (112 rows x 64 bf16 = 128 B/row)
constexpr int ACH = 16384;   // A chunk bytes (64 rows x 64 f32 = 256 B/row)

__device__ __forceinline__ float sigf(float x) { return 1.f / (1.f + __expf(-x)); }
__device__ __forceinline__ float tanhfast(float x) { return 2.f / (1.f + __expf(-2.f * x)) - 1.f; }

__device__ __forceinline__ short f2b(float x) {
  __hip_bfloat16 b = __float2bfloat16(x);
  return *reinterpret_cast<short*>(&b);
}

// global -> LDS direct DMA, 16B/lane. LDS dest wave-uniform (HW adds lane*16);
// global src per-lane. No register result -> compiler cannot serialize it.
__device__ __forceinline__ void gl_lds16(const void* g, void* l) {
  __builtin_amdgcn_global_load_lds(
      (const __attribute__((address_space(1))) unsigned int*)g,
      (__attribute__((address_space(3))) unsigned int*)l, 16, 0, 0);
}

// ---------------------------------------------------------------------------
// Prep: fold swapaxes(-1,-2) into weights. w2c CHUNK-MAJOR [15][112][64] bf16,
// PRE-SWIZZLED within each 128B row (elem kk ^= (n&7)<<3 i.e. byte ^ (n&7)<<4)
// so a LINEAR global_load_lds copy lands with the swizzled layout the GEMM's
// frag reads expect (rule #21: linear dest + inverse-swz source + swz read).
// Zero for k>=940 or n>=100 (lets A read garbage in the K-tail: x0).
// ---------------------------------------------------------------------------
__global__ void prep_kernel(const float* __restrict__ lin_w,
                            const float* __restrict__ b_wih,
                            __hip_bfloat16* __restrict__ w2c,
                            __hip_bfloat16* __restrict__ bw2) {
  int idx = blockIdx.x * 256 + threadIdx.x;
  if (idx < NP * 1024) {
    int n = idx >> 10, k = idx & 1023;
    if (k < 960) {
      float v = 0.f;
      if (n < 100 && k < K1) {
        int c10 = k / 94, rem = k - c10 * 94;
        int c2 = rem / 47, c47 = rem - c2 * 47;
        int f = c10 * 94 + c47 * 2 + c2;
        v = lin_w[n * K1 + f];
      }
      int c = k >> 6, kk = k & 63;
      w2c[c * 7168 + n * 64 + (kk ^ ((n & 7) << 3))] = __float2bfloat16(v);
    }
  } else {
    int i2 = idx - NP * 1024;
    if (i2 < 64 * 128) {
      int g = i2 >> 7, k = i2 & 127;
      bw2[i2] = __float2bfloat16((k < 100) ? b_wih[g * 100 + k] : 0.f);
    }
  }
}

// ---------------------------------------------------------------------------
// R10 GEMM: EVERYTHING through global_load_lds. Zero register-result loads in
// the K-loop (R8 proved the compiler serializes any reg-staged pipeline).
// 15 chunks of 64 k. A fp32 [64][256B] triple-buffered (2-chunk lead covers
// ~900cy HBM); B bf16 [112][128B] double-buffered (1-chunk lead, L2-hot).
// Counted vmcnt(4) at each barrier: only the newest A-DMAs stay in flight --
// the pipeline NEVER drains. f32->bf16 cvt at frag-read time (VALU, in MFMA
// shadow). A swizzle via per-lane DMA SOURCE addr; B pre-swizzled in prep.
// LDS: 3*16384 + 2*14336 = 77824 B -> 2 blocks/CU.
// ---------------------------------------------------------------------------
__global__ __launch_bounds__(256, 2)
void linear_gemm(const float* __restrict__ ch,
                 const __hip_bfloat16* __restrict__ w2c,
                 const float* __restrict__ lin_b,
                 __hip_bfloat16* __restrict__ out1) {
  __shared__ __align__(16) char smem[3 * ACH + 2 * BCH];   // 77824 B
  char* As = smem;                 // 3 bufs: 64 rows x 256 B (fp32, swz)
  char* Bs = smem + 3 * ACH;       // 2 bufs: 112 rows x 128 B (bf16, swz)

  const int tid = threadIdx.x;
  const int w = tid >> 6, lane = tid & 63;
  const int l16 = lane & 15, bq = lane >> 4;
  const int row0 = blockIdx.x * 64;

  // ---- A DMA: wave w stages its rows w*16..+15; 4 instrs x 1KB (4 rows).
  // Lane i -> local row w*16+4j+(i>>4); src byte = ((i&15)*16) ^ ((row&7)<<4)
  // within the row's 256B chunk-segment (inverse-swizzle on the source).
  auto dmaA = [&](int c, int buf) {
    char* dst = As + buf * ACH + w * 4096;
#pragma unroll
    for (int j = 0; j < 4; ++j) {
      const int row = w * 16 + 4 * j + (lane >> 4);
      const int inner = ((lane & 15) * 16) ^ ((row & 7) << 4);
      const char* src = (const char*)ch +
                        ((long)(row0 + row) * K1 + c * 64) * 4 + inner;
      if (c == 14 && inner >= 176) src = (const char*)ch;  // k>=940: x0 weights
      gl_lds16(src, dst + j * 1024);
    }
  };

  // ---- B DMA: 14 instrs x 1KB, linear (pre-swizzled source layout). ----
  auto dmaB = [&](int c, int buf) {
#pragma unroll
    for (int j = 0; j < 4; ++j) {
      const int t = w * 4 + j;
      if (t < 14)
        gl_lds16((const char*)w2c + c * BCH + t * 1024 + lane * 16,
                 Bs + buf * BCH + t * 1024);
    }
  };

  // ---- prologue: B0, A0 issued+waited; A1 left in flight ----
  dmaB(0, 0);
  dmaA(0, 0);
  dmaA(1, 1);
  asm volatile("s_waitcnt vmcnt(4)" ::: "memory");   // B0,A0 done; A1 in flight
  __builtin_amdgcn_s_barrier();
  __builtin_amdgcn_sched_barrier(0);

  f32x4 acc[7] = {};
  const int swzA = (l16 & 7) << 4;

#pragma unroll
  for (int c = 0; c < 15; ++c) {
    if (c + 1 < 15) dmaB(c + 1, (c + 1) & 1);     // 1-chunk lead (L2)
    if (c + 2 < 15) dmaA(c + 2, (c + 2) % 3);     // 2-chunk lead (HBM)
    const char* Ap = As + (c % 3) * ACH + (w * 16 + l16) * 256;
    const char* Bp = Bs + (c & 1) * BCH;
#pragma unroll
    for (int ks = 0; ks < 2; ++ks) {
      const int ab = ks * 128 + bq * 32;
      f32x4 a0 = *reinterpret_cast<const f32x4*>(Ap + (ab ^ swzA));
      f32x4 a1 = *reinterpret_cast<const f32x4*>(Ap + ((ab + 16) ^ swzA));
      bf16x8 af = {f2b(a0[0]), f2b(a0[1]), f2b(a0[2]), f2b(a0[3]),
                   f2b(a1[0]), f2b(a1[1]), f2b(a1[2]), f2b(a1[3])};
#pragma unroll
      for (int nt = 0; nt < 7; ++nt) {
        const int rowb = nt * 16 + l16;
        bf16x8 b = *reinterpret_cast<const bf16x8*>(
            Bp + rowb * 128 + ((ks * 64 + bq * 16) ^ ((rowb & 7) << 4)));
        acc[nt] = MFMA16(af, b, acc[nt]);
      }
    }
    if (c < 14) {
      asm volatile("s_waitcnt lgkmcnt(0)" ::: "memory");  // frag reads retired
      if (c == 13) asm volatile("s_waitcnt vmcnt(0)" ::: "memory");
      else         asm volatile("s_waitcnt vmcnt(4)" ::: "memory");  // keep A(c+2) in flight
      __builtin_amdgcn_s_barrier();
      __builtin_amdgcn_sched_barrier(0);
    }
  }

  // ---- epilogue: bias + relu -> out1 bf16 [32768][112] ----
#pragma unroll
  for (int nt = 0; nt < 7; ++nt) {
    const int col = nt * 16 + l16;
    const float bias = (col < 100) ? lin_b[col] : 0.f;
#pragma unroll
    for (int r = 0; r < 4; ++r) {
      float v = (col < 100) ? fmaxf(acc[nt][r] + bias, 0.f) : 0.f;
      out1[(long)(row0 + w * 16 + bq * 4 + r) * 112 + col] = __float2bfloat16(v);
    }
  }
}

// ---------------------------------------------------------------------------
// lstm_kernel (unchanged): stage out1 -> LDS, xg GEMM, beats LSTM, bars
// biLSTM. Block = 256 thr = 4 waves = 64 rows = 8 frac-seqs = 2 bar-seqs.
// ---------------------------------------------------------------------------
__global__ __launch_bounds__(256)
void lstm_kernel(const __hip_bfloat16* __restrict__ out1,
                 const __hip_bfloat16* __restrict__ bw2,
                 const float* __restrict__ bih,
                 const float* __restrict__ bhh,
                 const float* __restrict__ whh,
                 const float* __restrict__ fwih, const float* __restrict__ fwhh,
                 const float* __restrict__ fbih, const float* __restrict__ fbhh,
                 const float* __restrict__ rwih, const float* __restrict__ rwhh,
                 const float* __restrict__ rbih, const float* __restrict__ rbhh,
                 float* __restrict__ beats,
                 float* __restrict__ bars) {
  __shared__ __align__(16) __hip_bfloat16 out_s[64 * OSL];   // 17408 B
  __shared__ float xg_s[64 * 65];                            // 16640 B
  __shared__ float hlast[8][16];
  __shared__ float hb[2][32];
  __shared__ float gact[2][128];

  const int tid = threadIdx.x;
  const int w = tid >> 6, lane = tid & 63;
  const int l16 = lane & 15, bq = lane >> 4;
  const long rbase = (long)blockIdx.x * 64;

  // stage out1 [64][112] -> out_s [64][OSL], zero cols 112..127
#pragma unroll
  for (int it = 0; it < 4; ++it) {
    const int e = it * 256 + tid;        // 896 = 64 rows x 14 groups
    if (e < 896) {
      const int row = e / 14, g = e - row * 14;
      *reinterpret_cast<bf16x8*>(&out_s[row * OSL + g * 8]) =
          *reinterpret_cast<const bf16x8*>(&out1[(rbase + row) * 112 + g * 8]);
    }
  }
  if (tid < 128) {
    const int row = tid >> 1, c0 = 112 + (tid & 1) * 8;
    bf16x8 z = {0, 0, 0, 0, 0, 0, 0, 0};
    *reinterpret_cast<bf16x8*>(&out_s[row * OSL + c0]) = z;
  }
  __syncthreads();

  // ---- Phase B: xg[16 rows][64 gates], wave-private rows ----
  {
    bf16x8 av[4];
#pragma unroll
    for (int s = 0; s < 4; ++s)
      av[s] = *reinterpret_cast<const bf16x8*>(&out_s[(w * 16 + l16) * OSL + s * 32 + bq * 8]);
    f32x4 xacc[4] = {};
#pragma unroll
    for (int gt = 0; gt < 4; ++gt) {
#pragma unroll
      for (int s = 0; s < 4; ++s) {
        bf16x8 b = *reinterpret_cast<const bf16x8*>(&bw2[(gt * 16 + l16) * 128 + s * 32 + bq * 8]);
        xacc[gt] = MFMA16(av[s], b, xacc[gt]);
      }
    }
#pragma unroll
    for (int gt = 0; gt < 4; ++gt) {
      const int gate = gt * 16 + l16;
      const float bias = bih[gate] + bhh[gate];
#pragma unroll
      for (int r = 0; r < 4; ++r)
        xg_s[(w * 16 + bq * 4 + r) * 65 + gate] = xacc[gt][r] + bias;
    }
  }

  // ---- Phase C: beats LSTM, 2 sequences per wave, interleaved ----
  {
    const int cell = lane & 15;
    float wr[16];
#pragma unroll
    for (int u = 0; u < 16; ++u) wr[u] = whh[lane * 16 + u];
    float xv0[8], xv1[8];
#pragma unroll
    for (int t = 0; t < 8; ++t) {
      xv0[t] = xg_s[(w * 16 + t) * 65 + lane];
      xv1[t] = xg_s[(w * 16 + 8 + t) * 65 + lane];
    }
    float h0[16], h1[16];
#pragma unroll
    for (int u = 0; u < 16; ++u) { h0[u] = 0.f; h1[u] = 0.f; }
    float c0 = 0.f, c1 = 0.f;
    const long sg0 = (long)blockIdx.x * 8 + 2 * w;
    const long sg1 = sg0 + 1;
#pragma unroll
    for (int t = 0; t < 8; ++t) {
      float p0 = xv0[t], p1 = xv1[t];
#pragma unroll
      for (int u = 0; u < 16; ++u) { p0 += wr[u] * h0[u]; p1 += wr[u] * h1[u]; }
      const bool istanh = (lane >= 32 && lane < 48);
      float a0 = istanh ? tanhfast(p0) : sigf(p0);
      float a1 = istanh ? tanhfast(p1) : sigf(p1);
      float gi0 = __shfl(a0, cell),      gi1 = __shfl(a1, cell);
      float gf0 = __shfl(a0, cell + 16), gf1 = __shfl(a1, cell + 16);
      float gg0 = __shfl(a0, cell + 32), gg1 = __shfl(a1, cell + 32);
      float go0 = __shfl(a0, cell + 48), go1 = __shfl(a1, cell + 48);
      c0 = gf0 * c0 + gi0 * gg0;
      c1 = gf1 * c1 + gi1 * gg1;
      float hn0 = go0 * tanhfast(c0);
      float hn1 = go1 * tanhfast(c1);
#pragma unroll
      for (int u = 0; u < 16; ++u) { h0[u] = __shfl(hn0, u); h1[u] = __shfl(hn1, u); }
      if (lane < 16) {
        beats[sg0 * 128 + t * 16 + lane] = hn0;
        beats[sg1 * 128 + t * 16 + lane] = hn1;
        if (t == 7) {
          hlast[2 * w][lane]     = hn0;
          hlast[2 * w + 1][lane] = hn1;
        }
      }
    }
  }
  __syncthreads();  // publish hlast

  // ---- Phase D: bars biLSTM for this block's 2 bar-sequences ----
  {
    const int dir = tid >> 7, g = tid & 127;
    const float* wihp = dir ? rwih : fwih;
    const float* whhp = dir ? rwhh : fwhh;
    const float bias = dir ? (rbih[g] + rbhh[g]) : (fbih[g] + fbhh[g]);
    float wi[16], wh[32];
#pragma unroll
    for (int u = 0; u < 16; ++u) wi[u] = wihp[g * 16 + u];
#pragma unroll
    for (int u = 0; u < 32; ++u) wh[u] = whhp[g * 32 + u];
    for (int b2 = 0; b2 < 2; ++b2) {
      const int n = blockIdx.x * 2 + b2;
      float c = 0.f;
      if (g < 32) hb[dir][g] = 0.f;
      __syncthreads();
      for (int t = 0; t < 4; ++t) {
        const int tt = dir ? (3 - t) : t;
        float pre = bias;
#pragma unroll
        for (int u = 0; u < 16; ++u) pre += wi[u] * hlast[b2 * 4 + tt][u];
#pragma unroll
        for (int u = 0; u < 32; ++u) pre += wh[u] * hb[dir][u];
        gact[dir][g] = (g >= 64 && g < 96) ? tanhfast(pre) : sigf(pre);
        __syncthreads();
        if (g < 32) {
          c = gact[dir][32 + g] * c + gact[dir][g] * gact[dir][64 + g];
          float hn = gact[dir][96 + g] * tanhfast(c);
          hb[dir][g] = hn;
          bars[(n * 4 + tt) * 64 + dir * 32 + g] = hn;
        }
        __syncthreads();
      }
    }
  }
}

extern "C" void kernel_launch(void* const* d_in, const int* in_sizes, int n_in,
                              void* d_out, int out_size, void* d_ws, size_t ws_size,
                              hipStream_t stream) {
  const float* ch    = (const float*)d_in[0];
  const float* lin_w = (const float*)d_in[1];
  const float* lin_b = (const float*)d_in[2];
  const float* b_wih = (const float*)d_in[3];
  const float* b_whh = (const float*)d_in[4];
  const float* b_bih = (const float*)d_in[5];
  const float* b_bhh = (const float*)d_in[6];
  const float* f_wih = (const float*)d_in[7];
  const float* f_whh = (const float*)d_in[8];
  const float* f_bih = (const float*)d_in[9];
  const float* f_bhh = (const float*)d_in[10];
  const float* r_wih = (const float*)d_in[11];
  const float* r_whh = (const float*)d_in[12];
  const float* r_bih = (const float*)d_in[13];
  const float* r_bhh = (const float*)d_in[14];

  char* ws = (char*)d_ws;
  __hip_bfloat16* w2c  = (__hip_bfloat16*)ws;             // 15*7168*2 = 215040 B
  __hip_bfloat16* bw2  = (__hip_bfloat16*)(ws + 229376);  // 16384 B
  __hip_bfloat16* out1 = (__hip_bfloat16*)(ws + 245760);  // 32768*112*2 = 7340032 B
  float*          out  = (float*)d_out;

  prep_kernel<<<480, 256, 0, stream>>>(lin_w, b_wih, w2c, bw2);
  linear_gemm<<<512, 256, 0, stream>>>(ch, w2c, lin_b, out1);
  lstm_kernel<<<512, 256, 0, stream>>>(out1, bw2, b_bih, b_bhh, b_whh,
                                       f_wih, f_whh, f_bih, f_bhh,
                                       r_wih, r_whh, r_bih, r_bhh,
                                       out, out + 524288);
}